// Round 1
// baseline (4371.462 us; speedup 1.0000x reference)
//
#include <hip/hip_runtime.h>

// GraphSAGE on MI355X.
// Key insight: adj is 0.001-dense (avg degree ~16). Build CSR in one 1.07 GB
// scan of adj (the roofline), then do sparse mean-aggregation + fp32 dense
// GEMM per layer. No fp32 MFMA on CDNA4 -> vector FMA GEMM (only 2.7 GFLOP).

#define NN 16384          // nodes
#define FIN 128           // feature dim (all layer inputs)
#define CAP (1 << 19)     // edge capacity (expected ~268K, +/- ~500)

// ---- workspace layout (bytes) ----
// counters [0,256) | deg 64KB | offsets 16385*4 | cursor 64KB | deg_inv 64KB |
// pairs u64[CAP] | edge_src i32[CAP] | h1 8MB | h2 8MB   (total ~23.3 MB)
#define OFF_CNT   0u
#define OFF_DEG   256u
#define OFF_OFFS  65792u       // 256 + 65536
#define OFF_CUR   131584u      // 65792 + 65540 -> rounded to 256
#define OFF_DINV  197120u
#define OFF_PAIRS 262656u
#define OFF_ESRC  (262656u + 8u * CAP)                 // 4456960
#define OFF_H1    (OFF_ESRC + 4u * CAP)                // 6554112 (16B aligned)
#define OFF_H2    (OFF_H1 + 4u * NN * FIN)             // 14942720

// ---------- kernel 1: scan adj once, count degrees, emit (s,t) pairs ----------
__global__ void k_count(const float4* __restrict__ adj4, int* __restrict__ deg,
                        unsigned int* __restrict__ cnt,
                        unsigned long long* __restrict__ pairs) {
    const int total4 = NN * (NN / 4);          // 2^26
    const int stride = gridDim.x * blockDim.x;
    for (int i = blockIdx.x * blockDim.x + threadIdx.x; i < total4; i += stride) {
        float4 v = adj4[i];
        if (v.x == 0.f && v.y == 0.f && v.z == 0.f && v.w == 0.f) continue;
        int base = i << 2;
        int s = base >> 14;            // row (source)
        int t = base & (NN - 1);       // col (target), all 4 elems same row
        if (v.x != 0.f) {
            atomicAdd(&deg[t + 0], 1);
            unsigned int idx = atomicAdd(cnt, 1u);
            if (idx < CAP) pairs[idx] = ((unsigned long long)s << 32) | (unsigned)(t + 0);
        }
        if (v.y != 0.f) {
            atomicAdd(&deg[t + 1], 1);
            unsigned int idx = atomicAdd(cnt, 1u);
            if (idx < CAP) pairs[idx] = ((unsigned long long)s << 32) | (unsigned)(t + 1);
        }
        if (v.z != 0.f) {
            atomicAdd(&deg[t + 2], 1);
            unsigned int idx = atomicAdd(cnt, 1u);
            if (idx < CAP) pairs[idx] = ((unsigned long long)s << 32) | (unsigned)(t + 2);
        }
        if (v.w != 0.f) {
            atomicAdd(&deg[t + 3], 1);
            unsigned int idx = atomicAdd(cnt, 1u);
            if (idx < CAP) pairs[idx] = ((unsigned long long)s << 32) | (unsigned)(t + 3);
        }
    }
}

// ---------- kernel 2: exclusive scan deg -> offsets, cursors, deg_inv ----------
__global__ void k_scan(const int* __restrict__ deg, int* __restrict__ offs,
                       int* __restrict__ cur, float* __restrict__ dinv) {
    __shared__ int ps[256];
    int tid = threadIdx.x;
    int base = tid * 64;
    int local = 0;
    for (int j = 0; j < 64; ++j) local += deg[base + j];
    ps[tid] = local;
    __syncthreads();
    for (int ofs = 1; ofs < 256; ofs <<= 1) {
        int v = (tid >= ofs) ? ps[tid - ofs] : 0;
        __syncthreads();
        ps[tid] += v;
        __syncthreads();
    }
    int run = ps[tid] - local;   // exclusive prefix
    for (int j = 0; j < 64; ++j) {
        int d = deg[base + j];
        offs[base + j] = run;
        cur[base + j] = run;
        dinv[base + j] = d > 0 ? 1.0f / (float)d : 0.0f;
        run += d;
    }
    if (tid == 255) offs[NN] = run;
}

// ---------- kernel 3: bin pairs into CSR edge_src ----------
__global__ void k_bin(const unsigned long long* __restrict__ pairs,
                      const unsigned int* __restrict__ cnt,
                      int* __restrict__ cur, int* __restrict__ esrc) {
    unsigned int total = *cnt;
    if (total > CAP) total = CAP;
    unsigned int stride = gridDim.x * blockDim.x;
    for (unsigned int i = blockIdx.x * blockDim.x + threadIdx.x; i < total; i += stride) {
        unsigned long long p = pairs[i];
        int s = (int)(p >> 32);
        int t = (int)(p & 0xFFFFFFFFull);
        int pos = atomicAdd(&cur[t], 1);
        esrc[pos] = s;
    }
}

// ---------- kernel 4: fused SAGE layer (mean-agg + [Wl|Wr] GEMM + bias (+ReLU)) ----
// 32 nodes per block, 256 threads. LDS z[32][264] floats: slots [0,128)=agg,
// [128,256)=self row, 8 floats pad (bank-spread + keeps float4 alignment).
template <int FOUT, bool RELU>
__global__ __launch_bounds__(256) void k_layer(
    const float4* __restrict__ hin,    // [NN][32] float4
    float4* __restrict__ hout,         // [NN][FOUT/4]
    const int* __restrict__ esrc, const int* __restrict__ offs,
    const float* __restrict__ dinv,
    const float4* __restrict__ Wl4,    // [FOUT][32]
    const float4* __restrict__ b4,     // [FOUT/4]
    const float4* __restrict__ Wr4)    // [FOUT][32]
{
    constexpr int S4 = 66;             // float4 stride per node row (264 floats)
    __shared__ float4 z[32 * S4];
    const int tid = threadIdx.x;
    const int nodeBase = blockIdx.x * 32;

    // stage self rows: 1024 float4s, coalesced (32 consecutive tids = one row)
    #pragma unroll
    for (int r = 0; r < 4; ++r) {
        int g = tid + 256 * r;
        int n = g >> 5, j = g & 31;
        z[n * S4 + 32 + j] = hin[(nodeBase + n) * 32 + j];
    }

    // mean aggregation: 8-thread cluster per node, each thread covers 4 float4s
    {
        const int nl = tid >> 3;       // 0..31 node-local
        const int q = tid & 7;         // 0..7
        const int node = nodeBase + nl;
        const int e0 = offs[node], e1 = offs[node + 1];
        float4 acc[4];
        #pragma unroll
        for (int k = 0; k < 4; ++k) acc[k] = make_float4(0.f, 0.f, 0.f, 0.f);
        for (int e = e0; e < e1; ++e) {
            int s = esrc[e];
            const float4* row = hin + s * 32;
            #pragma unroll
            for (int k = 0; k < 4; ++k) {
                float4 v = row[q + 8 * k];
                acc[k].x += v.x; acc[k].y += v.y; acc[k].z += v.z; acc[k].w += v.w;
            }
        }
        const float di = dinv[node];
        #pragma unroll
        for (int k = 0; k < 4; ++k) {
            acc[k].x *= di; acc[k].y *= di; acc[k].z *= di; acc[k].w *= di;
            z[nl * S4 + q + 8 * k] = acc[k];
        }
    }
    __syncthreads();

    // GEMM: out[32 x FOUT] = [agg|self][32 x 256] @ [Wl|Wr]^T + b
    constexpr int TO = FOUT / 4;       // 32 (F=128) or 16 (F=64)
    constexpr int TN = 256 / TO;       // 8 or 16
    constexpr int NPT = 32 / TN;       // 4 or 2 nodes per thread
    const int to = tid % TO;
    const int tn = tid / TO;

    float acc[NPT][4];
    #pragma unroll
    for (int m = 0; m < NPT; ++m)
        #pragma unroll
        for (int r = 0; r < 4; ++r) acc[m][r] = 0.f;

    // part A: agg part (z slots [0,32)) x Wl
    #pragma unroll 4
    for (int k4 = 0; k4 < 32; ++k4) {
        float4 w0 = Wl4[(to * 4 + 0) * 32 + k4];
        float4 w1 = Wl4[(to * 4 + 1) * 32 + k4];
        float4 w2 = Wl4[(to * 4 + 2) * 32 + k4];
        float4 w3 = Wl4[(to * 4 + 3) * 32 + k4];
        #pragma unroll
        for (int m = 0; m < NPT; ++m) {
            float4 a = z[(tn * NPT + m) * S4 + k4];
            acc[m][0] += a.x * w0.x + a.y * w0.y + a.z * w0.z + a.w * w0.w;
            acc[m][1] += a.x * w1.x + a.y * w1.y + a.z * w1.z + a.w * w1.w;
            acc[m][2] += a.x * w2.x + a.y * w2.y + a.z * w2.z + a.w * w2.w;
            acc[m][3] += a.x * w3.x + a.y * w3.y + a.z * w3.z + a.w * w3.w;
        }
    }
    // part B: self part (z slots [32,64)) x Wr
    #pragma unroll 4
    for (int k4 = 0; k4 < 32; ++k4) {
        float4 w0 = Wr4[(to * 4 + 0) * 32 + k4];
        float4 w1 = Wr4[(to * 4 + 1) * 32 + k4];
        float4 w2 = Wr4[(to * 4 + 2) * 32 + k4];
        float4 w3 = Wr4[(to * 4 + 3) * 32 + k4];
        #pragma unroll
        for (int m = 0; m < NPT; ++m) {
            float4 a = z[(tn * NPT + m) * S4 + 32 + k4];
            acc[m][0] += a.x * w0.x + a.y * w0.y + a.z * w0.z + a.w * w0.w;
            acc[m][1] += a.x * w1.x + a.y * w1.y + a.z * w1.z + a.w * w1.w;
            acc[m][2] += a.x * w2.x + a.y * w2.y + a.z * w2.z + a.w * w2.w;
            acc[m][3] += a.x * w3.x + a.y * w3.y + a.z * w3.z + a.w * w3.w;
        }
    }

    // epilogue: +bias, optional ReLU, coalesced float4 store
    float4 bb = b4[to];
    #pragma unroll
    for (int m = 0; m < NPT; ++m) {
        float4 o;
        o.x = acc[m][0] + bb.x;
        o.y = acc[m][1] + bb.y;
        o.z = acc[m][2] + bb.z;
        o.w = acc[m][3] + bb.w;
        if (RELU) {
            o.x = fmaxf(o.x, 0.f); o.y = fmaxf(o.y, 0.f);
            o.z = fmaxf(o.z, 0.f); o.w = fmaxf(o.w, 0.f);
        }
        hout[(nodeBase + tn * NPT + m) * (FOUT / 4) + to] = o;
    }
}

extern "C" void kernel_launch(void* const* d_in, const int* in_sizes, int n_in,
                              void* d_out, int out_size, void* d_ws, size_t ws_size,
                              hipStream_t stream) {
    const float* x = (const float*)d_in[0];
    const float4* adj4 = (const float4*)d_in[1];
    const float4* Wl0 = (const float4*)d_in[2];
    const float4* b0 = (const float4*)d_in[3];
    const float4* Wr0 = (const float4*)d_in[4];
    const float4* Wl1 = (const float4*)d_in[5];
    const float4* b1 = (const float4*)d_in[6];
    const float4* Wr1 = (const float4*)d_in[7];
    const float4* Wl2 = (const float4*)d_in[8];
    const float4* b2 = (const float4*)d_in[9];
    const float4* Wr2 = (const float4*)d_in[10];

    char* ws = (char*)d_ws;
    unsigned int* cnt = (unsigned int*)(ws + OFF_CNT);
    int* deg = (int*)(ws + OFF_DEG);
    int* offs = (int*)(ws + OFF_OFFS);
    int* cur = (int*)(ws + OFF_CUR);
    float* dinv = (float*)(ws + OFF_DINV);
    unsigned long long* pairs = (unsigned long long*)(ws + OFF_PAIRS);
    int* esrc = (int*)(ws + OFF_ESRC);
    float4* h1 = (float4*)(ws + OFF_H1);
    float4* h2 = (float4*)(ws + OFF_H2);

    // zero counter + deg (ws is poisoned 0xAA before every call)
    hipMemsetAsync(ws, 0, OFF_OFFS, stream);

    // 1) scan adj (the 1.07 GB roofline read)
    k_count<<<2048, 256, 0, stream>>>(adj4, deg, cnt, pairs);
    // 2) CSR offsets / cursors / deg_inv
    k_scan<<<1, 256, 0, stream>>>(deg, offs, cur, dinv);
    // 3) bin edges
    k_bin<<<512, 256, 0, stream>>>(pairs, cnt, cur, esrc);
    // 4) three fused SAGE layers
    k_layer<128, true><<<NN / 32, 256, 0, stream>>>(
        (const float4*)x, h1, esrc, offs, dinv, Wl0, b0, Wr0);
    k_layer<128, true><<<NN / 32, 256, 0, stream>>>(
        (const float4*)h1, h2, esrc, offs, dinv, Wl1, b1, Wr1);
    k_layer<64, false><<<NN / 32, 256, 0, stream>>>(
        (const float4*)h2, (float4*)d_out, esrc, offs, dinv, Wl2, b2, Wr2);
}

// Round 2
// 1787.456 us; speedup vs baseline: 2.4456x; 2.4456x over previous
//
#include <hip/hip_runtime.h>

// GraphSAGE on MI355X.
// adj is 0.001-dense (avg degree ~16). Build CSR in one 1.07 GB scan of adj
// (the roofline), then sparse mean-aggregation + fp32 dense GEMM per layer.
// R1 fix: k_count's single-address global atomic (268K serialized, 2.9 ms)
// replaced with LDS-aggregated emission -> one global atomic per block (2048).

#define NN 16384          // nodes
#define FIN 128           // feature dim (all layer inputs)
#define CAP (1 << 19)     // edge capacity (expected ~268K)
#define LBUF 1024         // per-block LDS pair buffer (expected ~131 hits/block)

// ---- workspace layout (bytes) ----
#define OFF_CNT   0u
#define OFF_DEG   256u
#define OFF_OFFS  65792u       // 256 + 65536
#define OFF_CUR   131584u
#define OFF_DINV  197120u
#define OFF_PAIRS 262656u
#define OFF_ESRC  (262656u + 8u * CAP)                 // 4456960
#define OFF_H1    (OFF_ESRC + 4u * CAP)                // 6554112 (16B aligned)
#define OFF_H2    (OFF_H1 + 4u * NN * FIN)             // 14942720

// ---------- kernel 1: scan adj once, count degrees, emit (s,t) pairs ----------
// LDS-aggregated emission: LDS atomic append per hit, ONE global atomic per
// block at flush. deg[] atomics are distributed over 16K addresses (fine).
__global__ __launch_bounds__(256) void k_count(
    const float4* __restrict__ adj4, int* __restrict__ deg,
    unsigned int* __restrict__ cnt, unsigned long long* __restrict__ pairs) {
    __shared__ unsigned int lcnt;
    __shared__ unsigned int lbase;
    __shared__ unsigned long long lbuf[LBUF];
    const int tid = threadIdx.x;
    if (tid == 0) lcnt = 0;
    __syncthreads();

    const int total4 = NN * (NN / 4);          // 2^26
    const int stride = gridDim.x * blockDim.x;
    for (int i = blockIdx.x * 256 + tid; i < total4; i += stride) {
        float4 v = adj4[i];
        if (v.x == 0.f && v.y == 0.f && v.z == 0.f && v.w == 0.f) continue;
        int base = i << 2;
        int s = base >> 14;            // row (source)
        int t = base & (NN - 1);       // col (target)
        #pragma unroll
        for (int k = 0; k < 4; ++k) {
            float c = (k == 0) ? v.x : (k == 1) ? v.y : (k == 2) ? v.z : v.w;
            if (c != 0.f) {
                atomicAdd(&deg[t + k], 1);
                unsigned int idx = atomicAdd(&lcnt, 1u);   // LDS atomic: fast
                if (idx < LBUF)
                    lbuf[idx] = ((unsigned long long)s << 32) | (unsigned)(t + k);
            }
        }
    }
    __syncthreads();
    unsigned int total = lcnt;
    if (total > LBUF) total = LBUF;
    if (tid == 0) lbase = atomicAdd(cnt, total);           // 1 global atomic/block
    __syncthreads();
    unsigned int b = lbase;
    for (unsigned int j = tid; j < total; j += 256)
        if (b + j < CAP) pairs[b + j] = lbuf[j];
}

// ---------- kernel 2: exclusive scan deg -> offsets, cursors, deg_inv ----------
__global__ void k_scan(const int* __restrict__ deg, int* __restrict__ offs,
                       int* __restrict__ cur, float* __restrict__ dinv) {
    __shared__ int ps[256];
    int tid = threadIdx.x;
    int base = tid * 64;
    int local = 0;
    for (int j = 0; j < 64; ++j) local += deg[base + j];
    ps[tid] = local;
    __syncthreads();
    for (int ofs = 1; ofs < 256; ofs <<= 1) {
        int v = (tid >= ofs) ? ps[tid - ofs] : 0;
        __syncthreads();
        ps[tid] += v;
        __syncthreads();
    }
    int run = ps[tid] - local;   // exclusive prefix
    for (int j = 0; j < 64; ++j) {
        int d = deg[base + j];
        offs[base + j] = run;
        cur[base + j] = run;
        dinv[base + j] = d > 0 ? 1.0f / (float)d : 0.0f;
        run += d;
    }
    if (tid == 255) offs[NN] = run;
}

// ---------- kernel 3: bin pairs into CSR edge_src ----------
__global__ void k_bin(const unsigned long long* __restrict__ pairs,
                      const unsigned int* __restrict__ cnt,
                      int* __restrict__ cur, int* __restrict__ esrc) {
    unsigned int total = *cnt;
    if (total > CAP) total = CAP;
    unsigned int stride = gridDim.x * blockDim.x;
    for (unsigned int i = blockIdx.x * blockDim.x + threadIdx.x; i < total; i += stride) {
        unsigned long long p = pairs[i];
        int s = (int)(p >> 32);
        int t = (int)(p & 0xFFFFFFFFull);
        int pos = atomicAdd(&cur[t], 1);
        esrc[pos] = s;
    }
}

// ---------- kernel 4: fused SAGE layer (mean-agg + [Wl|Wr] GEMM + bias (+ReLU)) ----
// 16 nodes per block (1024 blocks -> 4 blocks/CU for gather latency hiding),
// 256 threads. LDS z[16][264] floats: [0,128)=agg, [128,256)=self, 8 pad.
template <int FOUT, bool RELU>
__global__ __launch_bounds__(256) void k_layer(
    const float4* __restrict__ hin,    // [NN][32] float4
    float4* __restrict__ hout,         // [NN][FOUT/4]
    const int* __restrict__ esrc, const int* __restrict__ offs,
    const float* __restrict__ dinv,
    const float4* __restrict__ Wl4,    // [FOUT][32]
    const float4* __restrict__ b4,     // [FOUT/4]
    const float4* __restrict__ Wr4)    // [FOUT][32]
{
    constexpr int S4 = 66;             // float4 stride per node row (264 floats)
    __shared__ float4 z[16 * S4];
    const int tid = threadIdx.x;
    const int nodeBase = blockIdx.x * 16;

    // stage self rows: 512 float4s, coalesced (32 consecutive tids = one row)
    #pragma unroll
    for (int r = 0; r < 2; ++r) {
        int g = tid + 256 * r;
        int n = g >> 5, j = g & 31;
        z[n * S4 + 32 + j] = hin[(nodeBase + n) * 32 + j];
    }

    // mean aggregation: 16-thread cluster per node, each thread covers 2 float4s
    {
        const int nl = tid >> 4;       // 0..15 node-local
        const int q = tid & 15;        // 0..15
        const int node = nodeBase + nl;
        const int e0 = offs[node], e1 = offs[node + 1];
        float4 acc0 = make_float4(0.f, 0.f, 0.f, 0.f);
        float4 acc1 = make_float4(0.f, 0.f, 0.f, 0.f);
        for (int e = e0; e < e1; ++e) {
            int s = esrc[e];
            const float4* row = hin + s * 32;
            float4 v0 = row[q];
            float4 v1 = row[q + 16];
            acc0.x += v0.x; acc0.y += v0.y; acc0.z += v0.z; acc0.w += v0.w;
            acc1.x += v1.x; acc1.y += v1.y; acc1.z += v1.z; acc1.w += v1.w;
        }
        const float di = dinv[node];
        acc0.x *= di; acc0.y *= di; acc0.z *= di; acc0.w *= di;
        acc1.x *= di; acc1.y *= di; acc1.z *= di; acc1.w *= di;
        z[nl * S4 + q] = acc0;
        z[nl * S4 + q + 16] = acc1;
    }
    __syncthreads();

    // GEMM: out[16 x FOUT] = [agg|self][16 x 256] @ [Wl|Wr]^T + b
    constexpr int TO = FOUT / 4;       // 32 (F=128) or 16 (F=64)
    constexpr int TN = 256 / TO;       // 8 or 16
    constexpr int NPT = 16 / TN;       // 2 or 1 nodes per thread
    const int to = tid % TO;
    const int tn = tid / TO;

    float acc[NPT][4];
    #pragma unroll
    for (int m = 0; m < NPT; ++m)
        #pragma unroll
        for (int r = 0; r < 4; ++r) acc[m][r] = 0.f;

    // part A: agg (z slots [0,32)) x Wl ; part B: self (z slots [32,64)) x Wr
    #pragma unroll 4
    for (int k4 = 0; k4 < 32; ++k4) {
        float4 w0 = Wl4[(to * 4 + 0) * 32 + k4];
        float4 w1 = Wl4[(to * 4 + 1) * 32 + k4];
        float4 w2 = Wl4[(to * 4 + 2) * 32 + k4];
        float4 w3 = Wl4[(to * 4 + 3) * 32 + k4];
        #pragma unroll
        for (int m = 0; m < NPT; ++m) {
            float4 a = z[(tn * NPT + m) * S4 + k4];
            acc[m][0] += a.x * w0.x + a.y * w0.y + a.z * w0.z + a.w * w0.w;
            acc[m][1] += a.x * w1.x + a.y * w1.y + a.z * w1.z + a.w * w1.w;
            acc[m][2] += a.x * w2.x + a.y * w2.y + a.z * w2.z + a.w * w2.w;
            acc[m][3] += a.x * w3.x + a.y * w3.y + a.z * w3.z + a.w * w3.w;
        }
    }
    #pragma unroll 4
    for (int k4 = 0; k4 < 32; ++k4) {
        float4 w0 = Wr4[(to * 4 + 0) * 32 + k4];
        float4 w1 = Wr4[(to * 4 + 1) * 32 + k4];
        float4 w2 = Wr4[(to * 4 + 2) * 32 + k4];
        float4 w3 = Wr4[(to * 4 + 3) * 32 + k4];
        #pragma unroll
        for (int m = 0; m < NPT; ++m) {
            float4 a = z[(tn * NPT + m) * S4 + 32 + k4];
            acc[m][0] += a.x * w0.x + a.y * w0.y + a.z * w0.z + a.w * w0.w;
            acc[m][1] += a.x * w1.x + a.y * w1.y + a.z * w1.z + a.w * w1.w;
            acc[m][2] += a.x * w2.x + a.y * w2.y + a.z * w2.z + a.w * w2.w;
            acc[m][3] += a.x * w3.x + a.y * w3.y + a.z * w3.z + a.w * w3.w;
        }
    }

    // epilogue: +bias, optional ReLU, coalesced float4 store
    float4 bb = b4[to];
    #pragma unroll
    for (int m = 0; m < NPT; ++m) {
        float4 o;
        o.x = acc[m][0] + bb.x;
        o.y = acc[m][1] + bb.y;
        o.z = acc[m][2] + bb.z;
        o.w = acc[m][3] + bb.w;
        if (RELU) {
            o.x = fmaxf(o.x, 0.f); o.y = fmaxf(o.y, 0.f);
            o.z = fmaxf(o.z, 0.f); o.w = fmaxf(o.w, 0.f);
        }
        hout[(nodeBase + tn * NPT + m) * (FOUT / 4) + to] = o;
    }
}

extern "C" void kernel_launch(void* const* d_in, const int* in_sizes, int n_in,
                              void* d_out, int out_size, void* d_ws, size_t ws_size,
                              hipStream_t stream) {
    const float* x = (const float*)d_in[0];
    const float4* adj4 = (const float4*)d_in[1];
    const float4* Wl0 = (const float4*)d_in[2];
    const float4* b0 = (const float4*)d_in[3];
    const float4* Wr0 = (const float4*)d_in[4];
    const float4* Wl1 = (const float4*)d_in[5];
    const float4* b1 = (const float4*)d_in[6];
    const float4* Wr1 = (const float4*)d_in[7];
    const float4* Wl2 = (const float4*)d_in[8];
    const float4* b2 = (const float4*)d_in[9];
    const float4* Wr2 = (const float4*)d_in[10];

    char* ws = (char*)d_ws;
    unsigned int* cnt = (unsigned int*)(ws + OFF_CNT);
    int* deg = (int*)(ws + OFF_DEG);
    int* offs = (int*)(ws + OFF_OFFS);
    int* cur = (int*)(ws + OFF_CUR);
    float* dinv = (float*)(ws + OFF_DINV);
    unsigned long long* pairs = (unsigned long long*)(ws + OFF_PAIRS);
    int* esrc = (int*)(ws + OFF_ESRC);
    float4* h1 = (float4*)(ws + OFF_H1);
    float4* h2 = (float4*)(ws + OFF_H2);

    // zero counter + deg (ws is poisoned 0xAA before every call)
    hipMemsetAsync(ws, 0, OFF_OFFS, stream);

    // 1) scan adj (the 1.07 GB roofline read)
    k_count<<<2048, 256, 0, stream>>>(adj4, deg, cnt, pairs);
    // 2) CSR offsets / cursors / deg_inv
    k_scan<<<1, 256, 0, stream>>>(deg, offs, cur, dinv);
    // 3) bin edges
    k_bin<<<512, 256, 0, stream>>>(pairs, cnt, cur, esrc);
    // 4) three fused SAGE layers
    k_layer<128, true><<<NN / 16, 256, 0, stream>>>(
        (const float4*)x, h1, esrc, offs, dinv, Wl0, b0, Wr0);
    k_layer<128, true><<<NN / 16, 256, 0, stream>>>(
        (const float4*)h1, h2, esrc, offs, dinv, Wl1, b1, Wr1);
    k_layer<64, false><<<NN / 16, 256, 0, stream>>>(
        (const float4*)h2, (float4*)d_out, esrc, offs, dinv, Wl2, b2, Wr2);
}

// Round 4
// 1534.956 us; speedup vs baseline: 2.8479x; 1.1645x over previous
//
#include <hip/hip_runtime.h>

// GraphSAGE on MI355X.
// adj is 0.001-dense (avg degree ~16). Build CSR in one 1.07 GB scan of adj
// (the roofline), then sparse mean-aggregation + fp32 dense GEMM per layer.
// R1: LDS-aggregated pair emission (1 global atomic/block, not per-edge).
// R2: pre-transposed weights Wt[256][FOUT] -> coalesced W streams in GEMM;
//     2-way MLP + nontemporal loads in k_count; 1024-thread scan.
// R3: fix build — __builtin_nontemporal_load needs a native vector type,
//     not HIP_vector_type<int,4>; use ext_vector_type(4) int.

#define NN 16384          // nodes
#define FIN 128           // feature dim (all layer inputs)
#define CAP (1 << 19)     // edge capacity (expected ~268K)
#define LBUF 1024         // per-block LDS pair buffer (expected ~131 hits/block)

typedef int iv4 __attribute__((ext_vector_type(4)));   // native vector for ntload

// ---- workspace layout (bytes) ----
#define OFF_CNT   0u
#define OFF_DEG   256u
#define OFF_OFFS  65792u                               // 256 + 65536
#define OFF_CUR   131584u
#define OFF_DINV  197120u
#define OFF_PAIRS 262656u
#define OFF_ESRC  (262656u + 8u * CAP)                 // 4456960
#define OFF_WT0   (OFF_ESRC + 4u * CAP)                // 6554112
#define OFF_WT1   (OFF_WT0 + 131072u)                  // Wt0 [256][128] f32
#define OFF_WT2   (OFF_WT1 + 131072u)                  // Wt1 [256][128] f32
#define OFF_H1    (OFF_WT2 + 65536u)                   // Wt2 [256][64] f32
#define OFF_H2    (OFF_H1 + 4u * NN * FIN)

// ---------- kernel 0: transpose [Wl;Wr] -> Wt[256][FOUT] ----------
// Wt[k][o] = k<128 ? Wl[o][k] : Wr[o][k-128]. Makes GEMM W-streams
// lane-contiguous (one 512B run per wave load instead of 64 cachelines).
__global__ void k_wt(const float* __restrict__ Wl0, const float* __restrict__ Wr0,
                     const float* __restrict__ Wl1, const float* __restrict__ Wr1,
                     const float* __restrict__ Wl2, const float* __restrict__ Wr2,
                     float* __restrict__ wt0, float* __restrict__ wt1,
                     float* __restrict__ wt2) {
    int g = blockIdx.x * 256 + threadIdx.x;
    if (g < 32768) {
        int k = g >> 7, o = g & 127;
        wt0[g] = (k < 128) ? Wl0[o * 128 + k] : Wr0[o * 128 + (k - 128)];
    } else if (g < 65536) {
        int gg = g - 32768;
        int k = gg >> 7, o = gg & 127;
        wt1[gg] = (k < 128) ? Wl1[o * 128 + k] : Wr1[o * 128 + (k - 128)];
    } else if (g < 81920) {
        int gg = g - 65536;
        int k = gg >> 6, o = gg & 63;
        wt2[gg] = (k < 128) ? Wl2[o * 128 + k] : Wr2[o * 128 + (k - 128)];
    }
}

// ---------- kernel 1: scan adj once, count degrees, emit (s,t) pairs ----------
__device__ __forceinline__ void emit_hits(iv4 v, int idx4, int* __restrict__ deg,
                                          unsigned int* lcnt,
                                          unsigned long long* lbuf) {
    if ((v.x | v.y | v.z | v.w) == 0) return;   // fp 0.0f is all-zero bits
    int base = idx4 << 2;
    int s = base >> 14;            // row (source)
    int t = base & (NN - 1);       // col (target)
    int w[4] = {v.x, v.y, v.z, v.w};
    #pragma unroll
    for (int k = 0; k < 4; ++k) {
        if (w[k] != 0) {
            atomicAdd(&deg[t + k], 1);
            unsigned int idx = atomicAdd(lcnt, 1u);   // LDS atomic
            if (idx < LBUF)
                lbuf[idx] = ((unsigned long long)s << 32) | (unsigned)(t + k);
        }
    }
}

__global__ __launch_bounds__(256) void k_count(
    const iv4* __restrict__ adj4, int* __restrict__ deg,
    unsigned int* __restrict__ cnt, unsigned long long* __restrict__ pairs) {
    __shared__ unsigned int lcnt;
    __shared__ unsigned int lbase;
    __shared__ unsigned long long lbuf[LBUF];
    const int tid = threadIdx.x;
    if (tid == 0) lcnt = 0;
    __syncthreads();

    // total4 = 2^26, stride = 2048*256 = 2^19, 64 iters of 2 independent loads
    const int stride = 2048 * 256;
    int i = blockIdx.x * 256 + tid;
    #pragma unroll 1
    for (int n = 0; n < 64; ++n, i += 2 * stride) {
        iv4 a = __builtin_nontemporal_load(&adj4[i]);
        iv4 b = __builtin_nontemporal_load(&adj4[i + stride]);
        emit_hits(a, i, deg, &lcnt, lbuf);
        emit_hits(b, i + stride, deg, &lcnt, lbuf);
    }
    __syncthreads();
    unsigned int total = lcnt;
    if (total > LBUF) total = LBUF;
    if (tid == 0) lbase = atomicAdd(cnt, total);           // 1 global atomic/block
    __syncthreads();
    unsigned int bb = lbase;
    for (unsigned int j = tid; j < total; j += 256)
        if (bb + j < CAP) pairs[bb + j] = lbuf[j];
}

// ---------- kernel 2: exclusive scan deg -> offsets, cursors, deg_inv ----------
__global__ __launch_bounds__(1024) void k_scan(
    const int* __restrict__ deg, int* __restrict__ offs,
    int* __restrict__ cur, float* __restrict__ dinv) {
    __shared__ int ps[1024];
    int tid = threadIdx.x;
    int base = tid * 16;
    int local = 0;
    #pragma unroll
    for (int j = 0; j < 16; ++j) local += deg[base + j];
    ps[tid] = local;
    __syncthreads();
    for (int ofs = 1; ofs < 1024; ofs <<= 1) {
        int v = (tid >= ofs) ? ps[tid - ofs] : 0;
        __syncthreads();
        ps[tid] += v;
        __syncthreads();
    }
    int run = ps[tid] - local;   // exclusive prefix
    #pragma unroll
    for (int j = 0; j < 16; ++j) {
        int d = deg[base + j];
        offs[base + j] = run;
        cur[base + j] = run;
        dinv[base + j] = d > 0 ? 1.0f / (float)d : 0.0f;
        run += d;
    }
    if (tid == 1023) offs[NN] = run;
}

// ---------- kernel 3: bin pairs into CSR edge_src ----------
__global__ void k_bin(const unsigned long long* __restrict__ pairs,
                      const unsigned int* __restrict__ cnt,
                      int* __restrict__ cur, int* __restrict__ esrc) {
    unsigned int total = *cnt;
    if (total > CAP) total = CAP;
    unsigned int stride = gridDim.x * blockDim.x;
    for (unsigned int i = blockIdx.x * blockDim.x + threadIdx.x; i < total; i += stride) {
        unsigned long long p = pairs[i];
        int s = (int)(p >> 32);
        int t = (int)(p & 0xFFFFFFFFull);
        int pos = atomicAdd(&cur[t], 1);
        esrc[pos] = s;
    }
}

// ---------- kernel 4: fused SAGE layer (mean-agg + Wt GEMM + bias (+ReLU)) ----
// 16 nodes/block, 1024 blocks (4/CU). LDS z[16][264] floats: float4 slots
// [0,32)=agg (k 0..127), [32,64)=self (k 128..255), 2 slots pad.
// GEMM: out[n][o] = sum_k z[n][k] * Wt[k][o], Wt rows are lane-contiguous.
template <int FOUT, bool RELU>
__global__ __launch_bounds__(256) void k_layer(
    const float4* __restrict__ hin,    // [NN][32] float4
    float4* __restrict__ hout,         // [NN][FOUT/4]
    const int* __restrict__ esrc, const int* __restrict__ offs,
    const float* __restrict__ dinv,
    const float4* __restrict__ Wt4,    // [256][FOUT/4]
    const float4* __restrict__ b4)     // [FOUT/4]
{
    constexpr int S4 = 66;             // float4 stride per node row
    __shared__ float4 z[16 * S4];
    const int tid = threadIdx.x;
    const int nodeBase = blockIdx.x * 16;

    // stage self rows: 512 float4s, coalesced
    #pragma unroll
    for (int r = 0; r < 2; ++r) {
        int g = tid + 256 * r;
        int n = g >> 5, j = g & 31;
        z[n * S4 + 32 + j] = hin[(nodeBase + n) * 32 + j];
    }

    // mean aggregation: 16-thread cluster per node, 2 float4s per thread
    {
        const int nl = tid >> 4;       // 0..15
        const int q = tid & 15;        // 0..15
        const int node = nodeBase + nl;
        const int e0 = offs[node], e1 = offs[node + 1];
        float4 acc0 = make_float4(0.f, 0.f, 0.f, 0.f);
        float4 acc1 = make_float4(0.f, 0.f, 0.f, 0.f);
        for (int e = e0; e < e1; ++e) {
            int s = esrc[e];
            const float4* row = hin + s * 32;
            float4 v0 = row[q];
            float4 v1 = row[q + 16];
            acc0.x += v0.x; acc0.y += v0.y; acc0.z += v0.z; acc0.w += v0.w;
            acc1.x += v1.x; acc1.y += v1.y; acc1.z += v1.z; acc1.w += v1.w;
        }
        const float di = dinv[node];
        acc0.x *= di; acc0.y *= di; acc0.z *= di; acc0.w *= di;
        acc1.x *= di; acc1.y *= di; acc1.z *= di; acc1.w *= di;
        z[nl * S4 + q] = acc0;
        z[nl * S4 + q + 16] = acc1;
    }
    __syncthreads();

    // GEMM
    constexpr int TO = FOUT / 4;       // 32 or 16
    constexpr int TN = 256 / TO;       // 8 or 16
    constexpr int NPT = 16 / TN;       // 2 or 1
    const int to = tid % TO;
    const int tn = tid / TO;

    float acc[NPT][4];
    #pragma unroll
    for (int m = 0; m < NPT; ++m)
        #pragma unroll
        for (int r = 0; r < 4; ++r) acc[m][r] = 0.f;

    #pragma unroll 4
    for (int k4 = 0; k4 < 64; ++k4) {
        // Wt rows 4k4..4k4+3, cols 4to..4to+3: contiguous across lanes
        float4 w0 = Wt4[(4 * k4 + 0) * TO + to];
        float4 w1 = Wt4[(4 * k4 + 1) * TO + to];
        float4 w2 = Wt4[(4 * k4 + 2) * TO + to];
        float4 w3 = Wt4[(4 * k4 + 3) * TO + to];
        #pragma unroll
        for (int m = 0; m < NPT; ++m) {
            float4 a = z[(tn * NPT + m) * S4 + k4];   // ks 4k4..4k4+3
            acc[m][0] += a.x * w0.x + a.y * w1.x + a.z * w2.x + a.w * w3.x;
            acc[m][1] += a.x * w0.y + a.y * w1.y + a.z * w2.y + a.w * w3.y;
            acc[m][2] += a.x * w0.z + a.y * w1.z + a.z * w2.z + a.w * w3.z;
            acc[m][3] += a.x * w0.w + a.y * w1.w + a.z * w2.w + a.w * w3.w;
        }
    }

    // epilogue: +bias, optional ReLU, coalesced float4 store
    float4 bb = b4[to];
    #pragma unroll
    for (int m = 0; m < NPT; ++m) {
        float4 o;
        o.x = acc[m][0] + bb.x;
        o.y = acc[m][1] + bb.y;
        o.z = acc[m][2] + bb.z;
        o.w = acc[m][3] + bb.w;
        if (RELU) {
            o.x = fmaxf(o.x, 0.f); o.y = fmaxf(o.y, 0.f);
            o.z = fmaxf(o.z, 0.f); o.w = fmaxf(o.w, 0.f);
        }
        hout[(nodeBase + tn * NPT + m) * (FOUT / 4) + to] = o;
    }
}

extern "C" void kernel_launch(void* const* d_in, const int* in_sizes, int n_in,
                              void* d_out, int out_size, void* d_ws, size_t ws_size,
                              hipStream_t stream) {
    const float* x = (const float*)d_in[0];
    const iv4* adj4 = (const iv4*)d_in[1];
    const float* Wl0 = (const float*)d_in[2];
    const float4* b0 = (const float4*)d_in[3];
    const float* Wr0 = (const float*)d_in[4];
    const float* Wl1 = (const float*)d_in[5];
    const float4* b1 = (const float4*)d_in[6];
    const float* Wr1 = (const float*)d_in[7];
    const float* Wl2 = (const float*)d_in[8];
    const float4* b2 = (const float4*)d_in[9];
    const float* Wr2 = (const float*)d_in[10];

    char* ws = (char*)d_ws;
    unsigned int* cnt = (unsigned int*)(ws + OFF_CNT);
    int* deg = (int*)(ws + OFF_DEG);
    int* offs = (int*)(ws + OFF_OFFS);
    int* cur = (int*)(ws + OFF_CUR);
    float* dinv = (float*)(ws + OFF_DINV);
    unsigned long long* pairs = (unsigned long long*)(ws + OFF_PAIRS);
    int* esrc = (int*)(ws + OFF_ESRC);
    float* wt0 = (float*)(ws + OFF_WT0);
    float* wt1 = (float*)(ws + OFF_WT1);
    float* wt2 = (float*)(ws + OFF_WT2);
    float4* h1 = (float4*)(ws + OFF_H1);
    float4* h2 = (float4*)(ws + OFF_H2);

    // zero counter + deg (ws is poisoned 0xAA before every call)
    (void)hipMemsetAsync(ws, 0, OFF_OFFS, stream);

    // 0) transpose weights (independent, tiny)
    k_wt<<<320, 256, 0, stream>>>(Wl0, Wr0, Wl1, Wr1, Wl2, Wr2, wt0, wt1, wt2);
    // 1) scan adj (the 1.07 GB roofline read)
    k_count<<<2048, 256, 0, stream>>>(adj4, deg, cnt, pairs);
    // 2) CSR offsets / cursors / deg_inv
    k_scan<<<1, 1024, 0, stream>>>(deg, offs, cur, dinv);
    // 3) bin edges
    k_bin<<<512, 256, 0, stream>>>(pairs, cnt, cur, esrc);
    // 4) three fused SAGE layers
    k_layer<128, true><<<NN / 16, 256, 0, stream>>>(
        (const float4*)x, h1, esrc, offs, dinv, (const float4*)wt0, b0);
    k_layer<128, true><<<NN / 16, 256, 0, stream>>>(
        (const float4*)h1, h2, esrc, offs, dinv, (const float4*)wt1, b1);
    k_layer<64, false><<<NN / 16, 256, 0, stream>>>(
        (const float4*)h2, (float4*)d_out, esrc, offs, dinv, (const float4*)wt2, b2);
}